// Round 3
// baseline (982.040 us; speedup 1.0000x reference)
//
#include <hip/hip_runtime.h>
#include <math.h>

#define B_    32
#define H_    32
#define KVH_  8
#define D_    128
#define HID_  4096
#define SEQ_  2048
#define CUR_  2047
#define QKVF_ 6144
#define SCALE_ 0.08838834764831845f   // 1/sqrt(128)

// x[32][4096] -> xT4 layout [k>>2][b][k&3]  (float granularity)
__global__ __launch_bounds__(256) void transpose_x(const float* __restrict__ x,
                                                   float* __restrict__ xT4) {
    int i = blockIdx.x * 256 + threadIdx.x;   // 131072 total
    int i4 = i & 3;
    int b  = (i >> 2) & 31;
    int kb = i >> 7;
    xT4[i] = x[b * HID_ + kb * 4 + i4];
}

// qkv[b][f] = dot(w_f, x_b); f: 0..4095=q, 4096..5119=k, 5120..6143=v
__global__ __launch_bounds__(256) void gemm_qkv(const float* __restrict__ wq,
                                                const float* __restrict__ wk,
                                                const float* __restrict__ wv,
                                                const float* __restrict__ xT4,
                                                float* __restrict__ qkv) {
    int b = threadIdx.x & 31;
    int f = blockIdx.x * 8 + (threadIdx.x >> 5);
    const float* wrow;                       // branch is wave-uniform (f spans 8)
    if (f < 4096)       wrow = wq + (size_t)f * HID_;
    else if (f < 5120)  wrow = wk + (size_t)(f - 4096) * HID_;
    else                wrow = wv + (size_t)(f - 5120) * HID_;
    const float4* w4p = (const float4*)wrow;
    const float4* x4p = (const float4*)xT4;
    float ax = 0.f, ay = 0.f, az = 0.f, aw = 0.f;
#pragma unroll 8
    for (int kb = 0; kb < 1024; ++kb) {
        float4 w  = w4p[kb];                 // half-wave broadcast, 16B
        float4 xv = x4p[kb * 32 + b];        // 512B coalesced per half-wave
        ax = fmaf(w.x, xv.x, ax);
        ay = fmaf(w.y, xv.y, ay);
        az = fmaf(w.z, xv.z, az);
        aw = fmaf(w.w, xv.w, aw);
    }
    qkv[b * QKVF_ + f] = (ax + ay) + (az + aw);
}

// RMSNorm + RoPE for q (32 heads) and k (8 heads). q pre-scaled by 1/sqrt(D).
__global__ __launch_bounds__(256) void norm_rope(const float* __restrict__ qkv,
                                                 const float* __restrict__ qnw,
                                                 const float* __restrict__ knw,
                                                 const float* __restrict__ cosT,
                                                 const float* __restrict__ sinT,
                                                 const int* __restrict__ pos_ids,
                                                 float* __restrict__ qhat,
                                                 float* __restrict__ khat) {
    int u = blockIdx.x * 4 + (threadIdx.x >> 6);   // 0..1279 = 32 b * 40 heads
    int l = threadIdx.x & 63;
    int b  = u / 40;
    int hh = u % 40;
    bool isq = hh < 32;
    const float* src = qkv + b * QKVF_ + (isq ? hh * D_ : HID_ + (hh - 32) * D_);
    float v0 = src[l];
    float v1 = src[l + 64];
    float ss = v0 * v0 + v1 * v1;
#pragma unroll
    for (int m = 1; m <= 32; m <<= 1) ss += __shfl_xor(ss, m, 64);
    float r = rsqrtf(ss * (1.0f / 128.0f) + 1e-6f);
    const float* nw = isq ? qnw : knw;
    float n0 = v0 * r * nw[l];
    float n1 = v1 * r * nw[l + 64];
    int pos = pos_ids[b];
    const float* cp = cosT + (size_t)pos * D_;
    const float* sp = sinT + (size_t)pos * D_;
    float o0 = n0 * cp[l]      - n1 * sp[l];       // d < 64:  x*c - x2*s
    float o1 = n1 * cp[l + 64] + n0 * sp[l + 64];  // d >= 64: x*c + x1*s
    if (isq) { o0 *= SCALE_; o1 *= SCALE_; }
    float* dst = isq ? (qhat + (size_t)(b * 32 + hh) * D_)
                     : (khat + (size_t)(b * 8 + (hh - 32)) * D_);
    dst[l]      = o0;
    dst[l + 64] = o1;
}

// One block per (b, kvh): 4 q-heads vs 2048 K/V rows. Output written
// transposed into aoutT4 layout [f>>2][b][f&3].
__global__ __launch_bounds__(1024) void attn(const float* __restrict__ qhat,
                                             const float* __restrict__ khat,
                                             const float* __restrict__ qkv,
                                             const float* __restrict__ kcache,
                                             const float* __restrict__ vcache,
                                             float* __restrict__ aoutT4) {
    __shared__ float sl[4 * SEQ_];            // scores -> p -> (reused) pO[16][512]
    __shared__ float mscr[4][4], lscr[4][4];
    int b    = blockIdx.x >> 3;
    int kvh  = blockIdx.x & 7;
    int wave = threadIdx.x >> 6;
    int lane = threadIdx.x & 63;
    int g    = lane >> 5;
    int dl   = lane & 31;
    int d0   = dl * 4;

    float4 q4[4];
#pragma unroll
    for (int h = 0; h < 4; ++h)
        q4[h] = *(const float4*)(qhat + (size_t)((b * 32 + kvh * 4 + h) * D_) + d0);

    const float* kbase = kcache + ((size_t)b * SEQ_ * KVH_ + kvh) * D_;
    const float* knew  = khat + (size_t)(b * 8 + kvh) * D_;
    int t0 = wave * 128 + g;

    // ---- pass 1: scores (each half-wave: one 128-float K row per iter) ----
#pragma unroll 4
    for (int it = 0; it < 64; ++it) {
        int row = t0 + it * 2;
        const float* kr = (row == CUR_) ? knew : (kbase + (size_t)row * (KVH_ * D_));
        float4 k4 = *(const float4*)(kr + d0);
#pragma unroll
        for (int h = 0; h < 4; ++h) {
            float p = fmaf(q4[h].x, k4.x,
                      fmaf(q4[h].y, k4.y,
                      fmaf(q4[h].z, k4.z, q4[h].w * k4.w)));
            p += __shfl_xor(p, 1, 64);
            p += __shfl_xor(p, 2, 64);
            p += __shfl_xor(p, 4, 64);
            p += __shfl_xor(p, 8, 64);
            p += __shfl_xor(p, 16, 64);
            if (dl == 0) sl[h * SEQ_ + row] = p;
        }
    }
    __syncthreads();

    // ---- softmax: p = exp(s - m), per-head partial sums into lscr ----
    {
        int hg = threadIdx.x >> 8;   // head 0..3 (256 threads each)
        int t  = threadIdx.x & 255;
        float m = -3.402823466e38f;
#pragma unroll
        for (int j = 0; j < 8; ++j) m = fmaxf(m, sl[hg * SEQ_ + t + j * 256]);
#pragma unroll
        for (int msk = 1; msk <= 32; msk <<= 1) m = fmaxf(m, __shfl_xor(m, msk, 64));
        int wg = (threadIdx.x >> 6) & 3;
        if (lane == 0) mscr[hg][wg] = m;
        __syncthreads();
        m = fmaxf(fmaxf(mscr[hg][0], mscr[hg][1]), fmaxf(mscr[hg][2], mscr[hg][3]));
        float lsum = 0.f;
#pragma unroll
        for (int j = 0; j < 8; ++j) {
            int idx = hg * SEQ_ + t + j * 256;
            float e = __expf(sl[idx] - m);
            sl[idx] = e;
            lsum += e;
        }
#pragma unroll
        for (int msk = 1; msk <= 32; msk <<= 1) lsum += __shfl_xor(lsum, msk, 64);
        if (lane == 0) lscr[hg][wg] = lsum;
        __syncthreads();
    }

    // ---- pass 2: O = p @ V ----
    const float* vbase = vcache + ((size_t)b * SEQ_ * KVH_ + kvh) * D_;
    const float* vnew  = qkv + b * QKVF_ + 5120 + kvh * D_;
    float4 acc[4];
#pragma unroll
    for (int h = 0; h < 4; ++h) acc[h] = make_float4(0.f, 0.f, 0.f, 0.f);
#pragma unroll 4
    for (int it = 0; it < 64; ++it) {
        int row = t0 + it * 2;
        const float* vr = (row == CUR_) ? vnew : (vbase + (size_t)row * (KVH_ * D_));
        float4 v4 = *(const float4*)(vr + d0);
#pragma unroll
        for (int h = 0; h < 4; ++h) {
            float pv = sl[h * SEQ_ + row];
            acc[h].x = fmaf(pv, v4.x, acc[h].x);
            acc[h].y = fmaf(pv, v4.y, acc[h].y);
            acc[h].z = fmaf(pv, v4.z, acc[h].z);
            acc[h].w = fmaf(pv, v4.w, acc[h].w);
        }
    }
#pragma unroll
    for (int h = 0; h < 4; ++h) {          // fold the two row-parities (g=0/1)
        acc[h].x += __shfl_xor(acc[h].x, 32, 64);
        acc[h].y += __shfl_xor(acc[h].y, 32, 64);
        acc[h].z += __shfl_xor(acc[h].z, 32, 64);
        acc[h].w += __shfl_xor(acc[h].w, 32, 64);
    }
    __syncthreads();          // all waves done reading p; safe to reuse sl
    if (g == 0) {
#pragma unroll
        for (int h = 0; h < 4; ++h)
            *(float4*)(sl + wave * 512 + h * 128 + d0) = acc[h];
    }
    __syncthreads();
    if (threadIdx.x < 512) {
        int h = threadIdx.x >> 7;
        int d = threadIdx.x & 127;
        float o = 0.f;
#pragma unroll
        for (int w = 0; w < 16; ++w) o += sl[w * 512 + h * 128 + d];
        o /= (lscr[h][0] + lscr[h][1] + lscr[h][2] + lscr[h][3]);
        int f = (kvh * 4 + h) * D_ + d;
        aoutT4[(size_t)(f >> 2) * 128 + b * 4 + (f & 3)] = o;
    }
}

// out[b][f] = dot(wo_f, attn_out_b)
__global__ __launch_bounds__(256) void gemm_o(const float* __restrict__ wo,
                                              const float* __restrict__ aT4,
                                              float* __restrict__ out) {
    int b = threadIdx.x & 31;
    int f = blockIdx.x * 8 + (threadIdx.x >> 5);
    const float4* w4p = (const float4*)(wo + (size_t)f * HID_);
    const float4* x4p = (const float4*)aT4;
    float ax = 0.f, ay = 0.f, az = 0.f, aw = 0.f;
#pragma unroll 8
    for (int kb = 0; kb < 1024; ++kb) {
        float4 w  = w4p[kb];
        float4 xv = x4p[kb * 32 + b];
        ax = fmaf(w.x, xv.x, ax);
        ay = fmaf(w.y, xv.y, ay);
        az = fmaf(w.z, xv.z, az);
        aw = fmaf(w.w, xv.w, aw);
    }
    out[b * HID_ + f] = (ax + ay) + (az + aw);
}

extern "C" void kernel_launch(void* const* d_in, const int* in_sizes, int n_in,
                              void* d_out, int out_size, void* d_ws, size_t ws_size,
                              hipStream_t stream) {
    const float* x      = (const float*)d_in[0];
    const float* wq     = (const float*)d_in[1];
    const float* wk     = (const float*)d_in[2];
    const float* wv     = (const float*)d_in[3];
    const float* wo     = (const float*)d_in[4];
    const float* qnw    = (const float*)d_in[5];
    const float* knw    = (const float*)d_in[6];
    const float* cosT   = (const float*)d_in[7];
    const float* sinT   = (const float*)d_in[8];
    const float* kcache = (const float*)d_in[9];
    const float* vcache = (const float*)d_in[10];
    const int*   pos    = (const int*)d_in[11];
    float* out = (float*)d_out;
    float* ws  = (float*)d_ws;

    float* xT4  = ws;              // 131072 floats
    float* qkv  = ws + 131072;     // 196608 floats
    float* qhat = ws + 327680;     // 131072 floats
    float* khat = ws + 458752;     // 32768 floats
    float* aT4  = ws + 491520;     // 131072 floats

    transpose_x<<<512, 256, 0, stream>>>(x, xT4);
    gemm_qkv<<<768, 256, 0, stream>>>(wq, wk, wv, xT4, qkv);
    norm_rope<<<320, 256, 0, stream>>>(qkv, qnw, knw, cosT, sinT, pos, qhat, khat);
    attn<<<256, 1024, 0, stream>>>(qhat, khat, qkv, kcache, vcache, aT4);
    gemm_o<<<512, 256, 0, stream>>>(wo, aT4, out);
}